// Round 3
// baseline (133.413 us; speedup 1.0000x reference)
//
#include <hip/hip_runtime.h>
#include <cstdint>
#include <cmath>

#define B_ 2
#define L_ 1024
#define D_ 256
#define U_ 32

typedef __attribute__((ext_vector_type(8))) short short8;
typedef __attribute__((ext_vector_type(4))) float floatx4;

// ---- workspace layout (bytes); total ~5.8 MB --------------------------------
#define OFF_FLAG 0u
#define OFF_Q2   1024u                    // 2048*32 fp32 = 256 KB
#define OFF_K2   (OFF_Q2 + 262144u)      // 256 KB
#define OFF_XT   (OFF_K2 + 262144u)      // [b][d][l] bf16, 1 MB
#define OFF_A    (OFF_XT + 1048576u)     // [b][q][k] bf16, 4 MB

__device__ __forceinline__ float bf2f(unsigned short u) {
    union { unsigned int i; float f; } v; v.i = ((unsigned int)u) << 16; return v.f;
}
__device__ __forceinline__ unsigned short f2bf(float f) {
    union { float f; unsigned int i; } v; v.f = f;
    unsigned int r = v.i + 0x7FFFu + ((v.i >> 16) & 1u);
    return (unsigned short)(r >> 16);
}

// ---------------------------------------------------------------------------
// Kernel 0: dtype sniff on EVEN ushorts (little-endian: even = fp32 LOW
// mantissa half = garbage exponent bits; bf16 data: even = genuine value).
// bf16 N(0,1) -> ~all plausible; fp32 low halves -> ~18% plausible.
// flag: 1 = fp32, 0 = bf16.
// ---------------------------------------------------------------------------
__global__ void detect_kernel(const unsigned short* __restrict__ xu, int* __restrict__ flag) {
    const int lane = threadIdx.x;
    float f = bf2f(xu[2 * lane]);
    bool plausible = (f == f) && (fabsf(f) < 1e4f) && (fabsf(f) > 1e-10f);
    unsigned long long m = __ballot(plausible);
    if (lane == 0) *flag = (__popcll(m) >= 60) ? 0 : 1;
}

// ---------------------------------------------------------------------------
// Kernel 1: q2[row][u] = 2*log2e*(x·Wt[:,u] + bh[u]);  k2[row][u] = 2*log2e*(x·Wx[u,:])
//           also writes xT[b][d][l] (bf16) for the MFMA B-operand.
// grid = B*L blocks, 64 threads. Dual-dtype reads via flag (wave-uniform).
// ---------------------------------------------------------------------------
__global__ void qk_xt_kernel(const void* __restrict__ x,  const void* __restrict__ Wt,
                             const void* __restrict__ Wx, const void* __restrict__ bh,
                             const int* __restrict__ flagp,
                             float* __restrict__ q2, float* __restrict__ k2,
                             unsigned short* __restrict__ xT) {
    const int row = blockIdx.x;              // b*L + l
    const int b = row >> 10, l = row & (L_ - 1);
    const int t = threadIdx.x;               // 0..63
    const int isf32 = *flagp;
    __shared__ __align__(16) float xs[D_];

    float4 f;
    if (isf32) {
        f = ((const float4*)((const float*)x + (size_t)row * D_))[t];
    } else {
        ushort4 v = ((const ushort4*)((const unsigned short*)x + (size_t)row * D_))[t];
        f = make_float4(bf2f(v.x), bf2f(v.y), bf2f(v.z), bf2f(v.w));
    }
    ((float4*)xs)[t] = f;

    // transpose write: xT[b][d][l], d = 4t..4t+3 (scattered 2B stores, small total)
    unsigned short* xtb = xT + (size_t)b * (D_ * L_) + l;
    xtb[(size_t)(4 * t + 0) * L_] = f2bf(f.x);
    xtb[(size_t)(4 * t + 1) * L_] = f2bf(f.y);
    xtb[(size_t)(4 * t + 2) * L_] = f2bf(f.z);
    xtb[(size_t)(4 * t + 3) * L_] = f2bf(f.w);

    __syncthreads();

    const float SC = 2.0f * 1.4426950408889634f;   // 2*log2(e): prescale for exp2 path
    float acc = 0.f;
    if (t < U_) {                                   // q side: Wt is [D][U], stride U
        if (isf32) {
            const float* wp = (const float*)Wt + t;
            #pragma unroll 8
            for (int d = 0; d < D_; ++d) acc = fmaf(xs[d], wp[d * U_], acc);
        } else {
            const unsigned short* wp = (const unsigned short*)Wt + t;
            #pragma unroll 8
            for (int d = 0; d < D_; ++d) acc = fmaf(xs[d], bf2f(wp[d * U_]), acc);
        }
        float bhv = isf32 ? ((const float*)bh)[t] : bf2f(((const unsigned short*)bh)[t]);
        q2[(size_t)row * U_ + t] = (acc + bhv) * SC;
    } else {                                        // k side: Wx is [U][D], stride 1
        const int u = t - U_;
        if (isf32) {
            const float* wp = (const float*)Wx + (size_t)u * D_;
            #pragma unroll 8
            for (int d = 0; d < D_; ++d) acc = fmaf(xs[d], wp[d], acc);
        } else {
            const unsigned short* wp = (const unsigned short*)Wx + (size_t)u * D_;
            #pragma unroll 8
            for (int d = 0; d < D_; ++d) acc = fmaf(xs[d], bf2f(wp[d]), acc);
        }
        k2[(size_t)row * U_ + u] = acc * SC;
    }
}

// ---------------------------------------------------------------------------
// Kernel 2: one wave per (b, qi).
// alpha_eff[ki] = sum_u (-2*Wa[u]) * rcp(exp2(q2+k2)+1)
// (constants ba and sum_u Wa[u] dropped -- softmax invariant). Stable softmax,
// normalized weights written as bf16 a[b][qi][ki].  grid = B*L, 64 threads.
// ---------------------------------------------------------------------------
__global__ void alpha_kernel(const float* __restrict__ q2, const float* __restrict__ k2,
                             const void* __restrict__ Wa, const int* __restrict__ flagp,
                             unsigned short* __restrict__ a) {
    const int row = blockIdx.x;              // b*L + qi
    const int b = row >> 10;
    const int lane = threadIdx.x;            // 0..63
    const int isf32 = *flagp;
    __shared__ float qs[U_], wm2[U_];
    if (lane < U_) {
        qs[lane]  = q2[(size_t)row * U_ + lane];
        float wav = isf32 ? ((const float*)Wa)[lane] : bf2f(((const unsigned short*)Wa)[lane]);
        wm2[lane] = -2.0f * wav;
    }
    __syncthreads();

    const float* kb = k2 + (size_t)b * (L_ * U_);
    float alpha[16];
    float amax = -1e30f;
    #pragma unroll
    for (int j = 0; j < 16; ++j) {
        const float* kr = kb + (size_t)(lane + 64 * j) * U_;
        float acc = 0.f;
        #pragma unroll
        for (int u4 = 0; u4 < U_ / 4; ++u4) {
            float4 kk = ((const float4*)kr)[u4];
            float kv[4] = {kk.x, kk.y, kk.z, kk.w};
            #pragma unroll
            for (int i = 0; i < 4; ++i) {
                int u = u4 * 4 + i;
                float tt = qs[u] + kv[i];                 // already scaled by 2*log2e
                float e  = exp2f(tt);                     // e^{2z}; inf/0 both benign
                float r  = __builtin_amdgcn_rcpf(e + 1.0f);
                acc = fmaf(wm2[u], r, acc);               // == Wa*tanh(z) up to key-const
            }
        }
        alpha[j] = acc;
        amax = fmaxf(amax, acc);
    }
    #pragma unroll
    for (int off = 32; off > 0; off >>= 1) amax = fmaxf(amax, __shfl_xor(amax, off, 64));

    const float L2E = 1.4426950408889634f;
    float s = 0.f;
    #pragma unroll
    for (int j = 0; j < 16; ++j) {
        alpha[j] = exp2f((alpha[j] - amax) * L2E);
        s += alpha[j];
    }
    #pragma unroll
    for (int off = 32; off > 0; off >>= 1) s += __shfl_xor(s, off, 64);
    const float rinv = __builtin_amdgcn_rcpf(s);

    unsigned short* ar = a + (size_t)row * L_;
    #pragma unroll
    for (int j = 0; j < 16; ++j) ar[lane + 64 * j] = f2bf(alpha[j] * rinv);
}

// ---------------------------------------------------------------------------
// Kernel 3: out[b][q][d] = sum_k a[b][q][k] * x[b][k][d], via MFMA 16x16x32 bf16.
// A-frag: a rows are k-contiguous -> 16B loads. B-frag from xT[d][k] -> 16B loads.
// One wave = 32x32 C tile (2x2 mfma). grid = B*32*8 = 512 blocks, 64 thr.
// Output dtype matches detected input dtype.
// ---------------------------------------------------------------------------
__global__ void out_gemm_kernel(const unsigned short* __restrict__ a,
                                const unsigned short* __restrict__ xT,
                                void* __restrict__ out, const int* __restrict__ flagp) {
    const int id = blockIdx.x;
    const int dt = id & 7;           // d-tile of 32
    const int qt = (id >> 3) & 31;   // q-tile of 32
    const int b  = id >> 8;
    const int lane = threadIdx.x;
    const int m  = lane & 15;
    const int ko = (lane >> 4) * 8;
    const int isf32 = *flagp;

    const unsigned short* ab = a  + (size_t)b * (L_ * L_) + (size_t)(qt * 32) * L_;
    const unsigned short* xb = xT + (size_t)b * (D_ * L_) + (size_t)(dt * 32) * L_;

    floatx4 acc00 = {0.f, 0.f, 0.f, 0.f}, acc01 = {0.f, 0.f, 0.f, 0.f};
    floatx4 acc10 = {0.f, 0.f, 0.f, 0.f}, acc11 = {0.f, 0.f, 0.f, 0.f};
    for (int k0 = 0; k0 < L_; k0 += 32) {
        short8 a0 = *(const short8*)(ab + (size_t)m        * L_ + k0 + ko);
        short8 a1 = *(const short8*)(ab + (size_t)(m + 16) * L_ + k0 + ko);
        short8 b0 = *(const short8*)(xb + (size_t)m        * L_ + k0 + ko);
        short8 b1 = *(const short8*)(xb + (size_t)(m + 16) * L_ + k0 + ko);
        acc00 = __builtin_amdgcn_mfma_f32_16x16x32_bf16(a0, b0, acc00, 0, 0, 0);
        acc01 = __builtin_amdgcn_mfma_f32_16x16x32_bf16(a0, b1, acc01, 0, 0, 0);
        acc10 = __builtin_amdgcn_mfma_f32_16x16x32_bf16(a1, b0, acc10, 0, 0, 0);
        acc11 = __builtin_amdgcn_mfma_f32_16x16x32_bf16(a1, b1, acc11, 0, 0, 0);
    }
    // C/D layout (m89-verified): col = lane&15, row = (lane>>4)*4 + reg
    const size_t obase = (size_t)b * (L_ * D_) + (size_t)(qt * 32) * D_ + dt * 32;
    const int col = lane & 15;
    const int rb  = (lane >> 4) * 4;
    if (isf32) {
        float* ob = (float*)out + obase;
        #pragma unroll
        for (int r = 0; r < 4; ++r) {
            ob[(size_t)(rb + r) * D_ + col]           = acc00[r];
            ob[(size_t)(rb + r) * D_ + 16 + col]      = acc01[r];
            ob[(size_t)(16 + rb + r) * D_ + col]      = acc10[r];
            ob[(size_t)(16 + rb + r) * D_ + 16 + col] = acc11[r];
        }
    } else {
        unsigned short* ob = (unsigned short*)out + obase;
        #pragma unroll
        for (int r = 0; r < 4; ++r) {
            ob[(size_t)(rb + r) * D_ + col]           = f2bf(acc00[r]);
            ob[(size_t)(rb + r) * D_ + 16 + col]      = f2bf(acc01[r]);
            ob[(size_t)(16 + rb + r) * D_ + col]      = f2bf(acc10[r]);
            ob[(size_t)(16 + rb + r) * D_ + 16 + col] = f2bf(acc11[r]);
        }
    }
}

extern "C" void kernel_launch(void* const* d_in, const int* in_sizes, int n_in,
                              void* d_out, int out_size, void* d_ws, size_t ws_size,
                              hipStream_t stream) {
    const void* x  = d_in[0];   // [B,L,D]  dtype sniffed at runtime
    const void* Wt = d_in[1];   // [D,U]
    const void* Wx = d_in[2];   // [U,D]
    const void* bh = d_in[3];   // [U]
    const void* Wa = d_in[4];   // [U,1]
    // d_in[5] = ba: constant shift before softmax -> mathematically irrelevant.

    char* ws = (char*)d_ws;
    int*   flag         = (int*)  (ws + OFF_FLAG);
    float* q2           = (float*)(ws + OFF_Q2);
    float* k2           = (float*)(ws + OFF_K2);
    unsigned short* xT  = (unsigned short*)(ws + OFF_XT);
    unsigned short* a   = (unsigned short*)(ws + OFF_A);

    detect_kernel<<<1, 64, 0, stream>>>((const unsigned short*)x, flag);
    qk_xt_kernel<<<B_ * L_, 64, 0, stream>>>(x, Wt, Wx, bh, flag, q2, k2, xT);
    alpha_kernel<<<B_ * L_, 64, 0, stream>>>(q2, k2, Wa, flag, a);
    out_gemm_kernel<<<B_ * 32 * 8, 64, 0, stream>>>(a, xT, d_out, flag);
}

// Round 4
// 131.807 us; speedup vs baseline: 1.0122x; 1.0122x over previous
//
#include <hip/hip_runtime.h>
#include <cstdint>
#include <cmath>

#define B_ 2
#define L_ 1024
#define D_ 256
#define U_ 32

typedef __attribute__((ext_vector_type(8))) short short8;
typedef __attribute__((ext_vector_type(4))) float floatx4;

// ---- workspace layout (bytes); total ~5.8 MB --------------------------------
#define OFF_Q2   0u                      // 2048*32 fp32 = 256 KB
#define OFF_K2   (OFF_Q2 + 262144u)      // 256 KB
#define OFF_XT   (OFF_K2 + 262144u)      // [b][d][l] bf16, 1 MB
#define OFF_A    (OFF_XT + 1048576u)     // [b][q][k] bf16, 4 MB

__device__ __forceinline__ float bf2f(unsigned short u) {
    union { unsigned int i; float f; } v; v.i = ((unsigned int)u) << 16; return v.f;
}
__device__ __forceinline__ unsigned short f2bf(float f) {
    union { float f; unsigned int i; } v; v.f = f;
    unsigned int r = v.i + 0x7FFFu + ((v.i >> 16) & 1u);
    return (unsigned short)(r >> 16);
}

// Inline dtype sniff (whole 64-thread block = one wave). Little-endian: for
// fp32 data the EVEN ushorts are low mantissa halves (garbage exponents, ~18%
// "plausible"); for bf16 data they are genuine N(0,1) values (~all plausible).
// Returns 1 = fp32, 0 = bf16. Costs one broadcast 128B load + ballot.
__device__ __forceinline__ int sniff_is_f32(const void* x) {
    const unsigned short* xu = (const unsigned short*)x;
    float f = bf2f(xu[2 * (threadIdx.x & 63)]);
    bool plausible = (f == f) && (fabsf(f) < 1e4f) && (fabsf(f) > 1e-10f);
    unsigned long long m = __ballot(plausible);
    return (__popcll(m) >= 60) ? 0 : 1;
}

// ---------------------------------------------------------------------------
// Kernel 1: q2[row][u] = 2*log2e*(x·Wt[:,u] + bh[u]);  k2[row][u] = 2*log2e*(x·Wx[u,:])
//           also writes xT[b][d][l] (bf16) for the MFMA B-operand.
// grid = B*L blocks, 64 threads.
// ---------------------------------------------------------------------------
__global__ void qk_xt_kernel(const void* __restrict__ x,  const void* __restrict__ Wt,
                             const void* __restrict__ Wx, const void* __restrict__ bh,
                             float* __restrict__ q2, float* __restrict__ k2,
                             unsigned short* __restrict__ xT) {
    const int row = blockIdx.x;              // b*L + l
    const int b = row >> 10, l = row & (L_ - 1);
    const int t = threadIdx.x;               // 0..63
    const int isf32 = sniff_is_f32(x);
    __shared__ __align__(16) float xs[D_];

    float4 f;
    if (isf32) {
        f = ((const float4*)((const float*)x + (size_t)row * D_))[t];
    } else {
        ushort4 v = ((const ushort4*)((const unsigned short*)x + (size_t)row * D_))[t];
        f = make_float4(bf2f(v.x), bf2f(v.y), bf2f(v.z), bf2f(v.w));
    }
    ((float4*)xs)[t] = f;

    // transpose write: xT[b][d][l], d = 4t..4t+3 (scattered 2B stores, 1 MB total)
    unsigned short* xtb = xT + (size_t)b * (D_ * L_) + l;
    xtb[(size_t)(4 * t + 0) * L_] = f2bf(f.x);
    xtb[(size_t)(4 * t + 1) * L_] = f2bf(f.y);
    xtb[(size_t)(4 * t + 2) * L_] = f2bf(f.z);
    xtb[(size_t)(4 * t + 3) * L_] = f2bf(f.w);

    __syncthreads();

    const float SC = 2.0f * 1.4426950408889634f;   // 2*log2(e): prescale for exp2 path
    float acc = 0.f;
    if (t < U_) {                                   // q side: Wt is [D][U], stride U
        if (isf32) {
            const float* wp = (const float*)Wt + t;
            #pragma unroll 8
            for (int d = 0; d < D_; ++d) acc = fmaf(xs[d], wp[d * U_], acc);
        } else {
            const unsigned short* wp = (const unsigned short*)Wt + t;
            #pragma unroll 8
            for (int d = 0; d < D_; ++d) acc = fmaf(xs[d], bf2f(wp[d * U_]), acc);
        }
        float bhv = isf32 ? ((const float*)bh)[t] : bf2f(((const unsigned short*)bh)[t]);
        q2[(size_t)row * U_ + t] = (acc + bhv) * SC;
    } else {                                        // k side: Wx is [U][D], stride 1
        const int u = t - U_;
        if (isf32) {
            const float* wp = (const float*)Wx + (size_t)u * D_;
            #pragma unroll 8
            for (int d = 0; d < D_; ++d) acc = fmaf(xs[d], wp[d], acc);
        } else {
            const unsigned short* wp = (const unsigned short*)Wx + (size_t)u * D_;
            #pragma unroll 8
            for (int d = 0; d < D_; ++d) acc = fmaf(xs[d], bf2f(wp[d]), acc);
        }
        k2[(size_t)row * U_ + u] = acc * SC;
    }
}

// ---------------------------------------------------------------------------
// Kernel 2: one wave per (b, qi).
// alpha_eff[ki] = sum_u (-2*Wa[u]) * rcp(exp2(q2+k2)+1)
// (constants ba and sum_u Wa[u] dropped -- softmax invariant). Stable softmax,
// normalized weights written as bf16 a[b][qi][ki].  grid = B*L, 64 threads.
// No LDS: q-row and Wa hoisted into registers (broadcast loads).
// ---------------------------------------------------------------------------
__global__ void alpha_kernel(const float* __restrict__ q2, const float* __restrict__ k2,
                             const void* __restrict__ Wa, const void* __restrict__ x,
                             unsigned short* __restrict__ a) {
    const int row = blockIdx.x;              // b*L + qi
    const int b = row >> 10;
    const int lane = threadIdx.x;            // 0..63
    const int isf32 = sniff_is_f32(x);

    float qv[U_], wv[U_];
    const float* qrow = q2 + (size_t)row * U_;
    #pragma unroll
    for (int i = 0; i < U_ / 4; ++i) {
        float4 t = ((const float4*)qrow)[i];
        qv[4*i+0] = t.x; qv[4*i+1] = t.y; qv[4*i+2] = t.z; qv[4*i+3] = t.w;
    }
    if (isf32) {
        #pragma unroll
        for (int i = 0; i < U_ / 4; ++i) {
            float4 t = ((const float4*)Wa)[i];
            wv[4*i+0] = -2.f*t.x; wv[4*i+1] = -2.f*t.y; wv[4*i+2] = -2.f*t.z; wv[4*i+3] = -2.f*t.w;
        }
    } else {
        #pragma unroll
        for (int i = 0; i < U_ / 4; ++i) {
            ushort4 t = ((const ushort4*)Wa)[i];
            wv[4*i+0] = -2.f*bf2f(t.x); wv[4*i+1] = -2.f*bf2f(t.y);
            wv[4*i+2] = -2.f*bf2f(t.z); wv[4*i+3] = -2.f*bf2f(t.w);
        }
    }

    const float* kb = k2 + (size_t)b * (L_ * U_);
    float alpha[16];
    float amax = -1e30f;
    #pragma unroll
    for (int j = 0; j < 16; ++j) {
        const float* kr = kb + (size_t)(lane + 64 * j) * U_;
        float acc = 0.f;
        #pragma unroll
        for (int u4 = 0; u4 < U_ / 4; ++u4) {
            float4 kk = ((const float4*)kr)[u4];
            float kv[4] = {kk.x, kk.y, kk.z, kk.w};
            #pragma unroll
            for (int i = 0; i < 4; ++i) {
                int u = u4 * 4 + i;
                float tt = qv[u] + kv[i];                 // already scaled by 2*log2e
                float e  = exp2f(tt);                     // e^{2z}; inf/0 both benign
                float r  = __builtin_amdgcn_rcpf(e + 1.0f);
                acc = fmaf(wv[u], r, acc);                // == Wa*tanh(z) up to key-const
            }
        }
        alpha[j] = acc;
        amax = fmaxf(amax, acc);
    }
    #pragma unroll
    for (int off = 32; off > 0; off >>= 1) amax = fmaxf(amax, __shfl_xor(amax, off, 64));

    const float L2E = 1.4426950408889634f;
    float s = 0.f;
    #pragma unroll
    for (int j = 0; j < 16; ++j) {
        alpha[j] = exp2f((alpha[j] - amax) * L2E);
        s += alpha[j];
    }
    #pragma unroll
    for (int off = 32; off > 0; off >>= 1) s += __shfl_xor(s, off, 64);
    const float rinv = __builtin_amdgcn_rcpf(s);

    unsigned short* ar = a + (size_t)row * L_;
    #pragma unroll
    for (int j = 0; j < 16; ++j) ar[lane + 64 * j] = f2bf(alpha[j] * rinv);
}

// ---------------------------------------------------------------------------
// Kernel 3: out[b][q][d] = sum_k a[b][q][k] * x[b][k][d], via MFMA 16x16x32 bf16.
// A-frag: a rows are k-contiguous -> 16B loads. B-frag from xT[d][k] -> 16B loads.
// One wave = 32x32 C tile (2x2 mfma). grid = B*32*8 = 512 blocks, 64 thr.
// Output dtype matches sniffed input dtype (fp32 expected).
// ---------------------------------------------------------------------------
__global__ void out_gemm_kernel(const unsigned short* __restrict__ a,
                                const unsigned short* __restrict__ xT,
                                const void* __restrict__ x,
                                void* __restrict__ out) {
    const int id = blockIdx.x;
    const int dt = id & 7;           // d-tile of 32
    const int qt = (id >> 3) & 31;   // q-tile of 32
    const int b  = id >> 8;
    const int lane = threadIdx.x;
    const int m  = lane & 15;
    const int ko = (lane >> 4) * 8;
    const int isf32 = sniff_is_f32(x);

    const unsigned short* ab = a  + (size_t)b * (L_ * L_) + (size_t)(qt * 32) * L_;
    const unsigned short* xb = xT + (size_t)b * (D_ * L_) + (size_t)(dt * 32) * L_;

    floatx4 acc00 = {0.f, 0.f, 0.f, 0.f}, acc01 = {0.f, 0.f, 0.f, 0.f};
    floatx4 acc10 = {0.f, 0.f, 0.f, 0.f}, acc11 = {0.f, 0.f, 0.f, 0.f};
    for (int k0 = 0; k0 < L_; k0 += 32) {
        short8 a0 = *(const short8*)(ab + (size_t)m        * L_ + k0 + ko);
        short8 a1 = *(const short8*)(ab + (size_t)(m + 16) * L_ + k0 + ko);
        short8 b0 = *(const short8*)(xb + (size_t)m        * L_ + k0 + ko);
        short8 b1 = *(const short8*)(xb + (size_t)(m + 16) * L_ + k0 + ko);
        acc00 = __builtin_amdgcn_mfma_f32_16x16x32_bf16(a0, b0, acc00, 0, 0, 0);
        acc01 = __builtin_amdgcn_mfma_f32_16x16x32_bf16(a0, b1, acc01, 0, 0, 0);
        acc10 = __builtin_amdgcn_mfma_f32_16x16x32_bf16(a1, b0, acc10, 0, 0, 0);
        acc11 = __builtin_amdgcn_mfma_f32_16x16x32_bf16(a1, b1, acc11, 0, 0, 0);
    }
    // C/D layout (m89-verified): col = lane&15, row = (lane>>4)*4 + reg
    const size_t obase = (size_t)b * (L_ * D_) + (size_t)(qt * 32) * D_ + dt * 32;
    const int col = lane & 15;
    const int rb  = (lane >> 4) * 4;
    if (isf32) {
        float* ob = (float*)out + obase;
        #pragma unroll
        for (int r = 0; r < 4; ++r) {
            ob[(size_t)(rb + r) * D_ + col]           = acc00[r];
            ob[(size_t)(rb + r) * D_ + 16 + col]      = acc01[r];
            ob[(size_t)(16 + rb + r) * D_ + col]      = acc10[r];
            ob[(size_t)(16 + rb + r) * D_ + 16 + col] = acc11[r];
        }
    } else {
        unsigned short* ob = (unsigned short*)out + obase;
        #pragma unroll
        for (int r = 0; r < 4; ++r) {
            ob[(size_t)(rb + r) * D_ + col]           = f2bf(acc00[r]);
            ob[(size_t)(rb + r) * D_ + 16 + col]      = f2bf(acc01[r]);
            ob[(size_t)(16 + rb + r) * D_ + col]      = f2bf(acc10[r]);
            ob[(size_t)(16 + rb + r) * D_ + 16 + col] = f2bf(acc11[r]);
        }
    }
}

extern "C" void kernel_launch(void* const* d_in, const int* in_sizes, int n_in,
                              void* d_out, int out_size, void* d_ws, size_t ws_size,
                              hipStream_t stream) {
    const void* x  = d_in[0];   // [B,L,D]  dtype sniffed at runtime (fp32 expected)
    const void* Wt = d_in[1];   // [D,U]
    const void* Wx = d_in[2];   // [U,D]
    const void* bh = d_in[3];   // [U]
    const void* Wa = d_in[4];   // [U,1]
    // d_in[5] = ba: constant shift before softmax -> mathematically irrelevant.

    char* ws = (char*)d_ws;
    float* q2           = (float*)(ws + OFF_Q2);
    float* k2           = (float*)(ws + OFF_K2);
    unsigned short* xT  = (unsigned short*)(ws + OFF_XT);
    unsigned short* a   = (unsigned short*)(ws + OFF_A);

    qk_xt_kernel<<<B_ * L_, 64, 0, stream>>>(x, Wt, Wx, bh, q2, k2, xT);
    alpha_kernel<<<B_ * L_, 64, 0, stream>>>(q2, k2, Wa, x, a);
    out_gemm_kernel<<<B_ * 32 * 8, 64, 0, stream>>>(a, xT, x, d_out);
}